// Round 5
// baseline (400.352 us; speedup 1.0000x reference)
//
#include <hip/hip_runtime.h>

typedef __attribute__((ext_vector_type(8))) _Float16 half8;
typedef __attribute__((ext_vector_type(4))) float f32x4;

#define BN_EPS 1e-5f
#define LOG2E 1.4426950408889634f

__device__ __forceinline__ void async_copy16(const void* g, void* l) {
  __builtin_amdgcn_global_load_lds((const __attribute__((address_space(1))) void*)g,
                                   (__attribute__((address_space(3))) void*)l,
                                   16, 0, 0);
}

// ---------------- kernel 1: x (B,C,N) fp32 -> xT (B,N,C) fp16 ----------------
__global__ void k_transpose(const float* __restrict__ x, _Float16* __restrict__ xT) {
  __shared__ float tile[64][65];
  int n0 = blockIdx.x * 64, c0 = blockIdx.y * 64, b = blockIdx.z;
  const float* xb = x + (size_t)b * 512 * 4096;
  int t = threadIdx.x;
#pragma unroll
  for (int rep = 0; rep < 16; ++rep) {
    int idx = rep * 256 + t;
    int r = idx >> 6, cc = idx & 63;
    tile[r][cc] = xb[(size_t)(c0 + r) * 4096 + n0 + cc];
  }
  __syncthreads();
  _Float16* xTb = xT + (size_t)b * 4096 * 512;
#pragma unroll
  for (int rep = 0; rep < 16; ++rep) {
    int idx = rep * 256 + t;
    int r = idx >> 6, cc = idx & 63;
    xTb[(size_t)(n0 + r) * 512 + c0 + cc] = (_Float16)tile[cc][r];
  }
}

// ---------------- kernel 2: W_all (640x512) fp16 = [Wq; Wk; Wv] ----------------
__global__ void k_wall(const float* __restrict__ Wq, const float* __restrict__ Wk,
                       const float* __restrict__ Wv, _Float16* __restrict__ W_all) {
  int i = blockIdx.x * 256 + threadIdx.x;
  if (i >= 640 * 512) return;
  int m = i >> 9, c = i & 511;
  float v;
  if (m < 64) v = Wq[m * 512 + c];
  else if (m < 128) v = Wk[(m - 64) * 512 + c];
  else v = Wv[(m - 128) * 512 + c];
  W_all[i] = (_Float16)v;
}

// ---------------- kernel 3: proj GEMM ----------------
// epilogue: q scaled by log2(e) so flash softmax can use native exp2.
__global__ __launch_bounds__(256) void k_proj(
    const _Float16* __restrict__ W_all, const _Float16* __restrict__ xT,
    const float* __restrict__ bq, const float* __restrict__ bk,
    const float* __restrict__ gamma, const float* __restrict__ beta,
    const float* __restrict__ mean, const float* __restrict__ var,
    _Float16* __restrict__ q_buf, _Float16* __restrict__ kT_buf,
    _Float16* __restrict__ v_buf) {
  __shared__ __align__(16) _Float16 A_lds[128 * 32];
  __shared__ __align__(16) _Float16 B_lds[128 * 32];
  int nt = blockIdx.x, mt = blockIdx.y, b = blockIdx.z;
  int t = threadIdx.x, w = t >> 6, lane = t & 63;
  int quad = lane >> 4, l16 = lane & 15;
  int moff = (w & 1) * 64, noff = (w >> 1) * 64;

  f32x4 acc[4][4] = {};

  for (int kk = 0; kk < 16; ++kk) {
    int kc = kk * 32;
#pragma unroll
    for (int c = 0; c < 2; ++c) {
      int row = (w * 2 + c) * 16 + (lane >> 2);
      int kseg = (lane & 3) * 8;
      async_copy16(W_all + (size_t)(mt * 128 + row) * 512 + kc + kseg,
                   (char*)A_lds + (w * 2 + c) * 1024 + lane * 16);
      async_copy16(xT + ((size_t)b * 4096 + nt * 128 + row) * 512 + kc + kseg,
                   (char*)B_lds + (w * 2 + c) * 1024 + lane * 16);
    }
    __syncthreads();
    half8 a[4], bb[4];
#pragma unroll
    for (int mi = 0; mi < 4; ++mi)
      a[mi] = *(const half8*)&A_lds[(moff + 16 * mi + l16) * 32 + 8 * quad];
#pragma unroll
    for (int ni = 0; ni < 4; ++ni)
      bb[ni] = *(const half8*)&B_lds[(noff + 16 * ni + l16) * 32 + 8 * quad];
#pragma unroll
    for (int mi = 0; mi < 4; ++mi)
#pragma unroll
      for (int ni = 0; ni < 4; ++ni)
        acc[mi][ni] = __builtin_amdgcn_mfma_f32_16x16x32_f16(a[mi], bb[ni], acc[mi][ni], 0, 0, 0);
    __syncthreads();
  }

  size_t bN = (size_t)b * 4096;
#pragma unroll
  for (int mi = 0; mi < 4; ++mi) {
    int mbase = mt * 128 + moff + 16 * mi + 4 * quad;
#pragma unroll
    for (int ni = 0; ni < 4; ++ni) {
      int n = nt * 128 + noff + 16 * ni + l16;
#pragma unroll
      for (int i = 0; i < 4; ++i) {
        int m = mbase + i;
        float val = acc[mi][ni][i];
        if (m < 64) {
          q_buf[(bN + n) * 64 + m] = (_Float16)((val + bq[m]) * LOG2E);
        } else if (m < 128) {
          kT_buf[(bN + n) * 64 + (m - 64)] = (_Float16)(val + bk[m - 64]);
        } else {
          int vv = m - 128;
          float sc = gamma[vv] * rsqrtf(var[vv] + BN_EPS);
          float sh = beta[vv] - mean[vv] * sc;
          float r = val * sc + sh;
          v_buf[((size_t)b * 512 + vv) * 4096 + n] = (_Float16)(r > 0.f ? r : 0.f);
        }
      }
    }
  }
}

// ---------------- kernel 4: flash attention, software-pipelined ----------------
// 256 blocks (round-0 cache geometry: bx&7 = batch -> XCD affinity, V 4MB/XCD in L2).
// 512 thr / 8 waves; wave w: S strip rows [16w,16w+16), O chunk V-cols [64w,64w+64).
// Pipeline: interval t does rescale(t) + PV(t) overlapped with QK(t+1)+softmax(t+1).
// One barrier/iter; P/alpha/K double-buffered; V prefetched in registers.
// Round-4 (kept): wave stagger (waves 4..7 PV-first) + s_setprio around MFMA
// clusters -> breaks the phase convoy (262 -> 242 us, MfmaUtil 24 -> 27).
// Round-5: defer-max (T13, THR=8, exact): only raise the running max when the
// tile max exceeds it by >8 exp2-units, so alpha == 1.0 on nearly every iter and
// the __any-guarded 128-mul rescale is skipped; shortens the softmax dep chain.
// P <= 2^8 = 256 (fp16-safe); normalization cancels the scale.
__global__ __launch_bounds__(512, 2) void k_flash(
    const _Float16* __restrict__ q_buf, const _Float16* __restrict__ kT_buf,
    const _Float16* __restrict__ v_buf, float* __restrict__ out) {
  __shared__ __align__(16) _Float16 P_lds[2][128 * 72];
  __shared__ __align__(16) _Float16 K_lds[2][64 * 64];
  __shared__ __align__(16) float alpha_lds[2][128];
  __shared__ __align__(16) float l_lds[128];
  int bx = blockIdx.x;
  int b = bx & 7;
  int n0 = (bx >> 3) * 128;
  int t = threadIdx.x, w = t >> 6, lane = t & 63, quad = lane >> 4, l16 = lane & 15;
  const _Float16* qb = q_buf + (size_t)b * 4096 * 64;
  const char* kbb = (const char*)(kT_buf + (size_t)b * 4096 * 64);
  const _Float16* vp = v_buf + (size_t)b * 512 * 4096 + (size_t)(64 * w + l16) * 4096 + 8 * quad;

  bool pv_first = (w >= 4);  // wave-uniform; SIMD s hosts {s: qk-first, s+4: pv-first}

  int st_r = w * 8 + (lane >> 3);
  int st_c = (lane & 7) ^ (st_r & 7);
  int st_dst = w * 1024 + lane * 16;
  int st_src = st_r * 128 + st_c * 16;

  half8 aq[2];
#pragma unroll
  for (int s = 0; s < 2; ++s)
    aq[s] = *(const half8*)&qb[(size_t)(n0 + 16 * w + l16) * 64 + 32 * s + 8 * quad];

  f32x4 o[8][4] = {};
  float m_st[4], l_st[4];
#pragma unroll
  for (int i = 0; i < 4; ++i) { m_st[i] = -1e30f; l_st[i] = 0.f; }

  // QK(block) from K_lds buffer + online softmax -> P/alpha buffers, update m/l
  auto qk_softmax = [&](const _Float16* Kb, _Float16* Pb, float* Ab) {
    f32x4 sc[4];
    __builtin_amdgcn_s_setprio(1);
#pragma unroll
    for (int ct = 0; ct < 4; ++ct) {
      int row = 16 * ct + l16;
      int sw = (row & 7) * 16;
      half8 k0 = *(const half8*)((const char*)Kb + row * 128 + ((quad * 16) ^ sw));
      half8 k1 = *(const half8*)((const char*)Kb + row * 128 + (((4 + quad) * 16) ^ sw));
      f32x4 sa = {0.f, 0.f, 0.f, 0.f};
      sa = __builtin_amdgcn_mfma_f32_16x16x32_f16(aq[0], k0, sa, 0, 0, 0);
      sa = __builtin_amdgcn_mfma_f32_16x16x32_f16(aq[1], k1, sa, 0, 0, 0);
      sc[ct] = sa;
    }
    __builtin_amdgcn_s_setprio(0);
#pragma unroll
    for (int i = 0; i < 4; ++i) {
      float mxi = fmaxf(fmaxf(sc[0][i], sc[1][i]), fmaxf(sc[2][i], sc[3][i]));
#pragma unroll
      for (int off = 1; off < 16; off <<= 1) mxi = fmaxf(mxi, __shfl_xor(mxi, off));
      float mnew = (mxi > m_st[i] + 8.f) ? mxi : m_st[i];  // defer-max (exact)
      float alpha_i = exp2f(m_st[i] - mnew);
      m_st[i] = mnew;
      float rsum = 0.f;
#pragma unroll
      for (int ct = 0; ct < 4; ++ct) {
        float pv = exp2f(sc[ct][i] - mnew);
        Pb[(16 * w + 4 * quad + i) * 72 + 16 * ct + l16] = (_Float16)pv;
        rsum += pv;
      }
      l_st[i] = l_st[i] * alpha_i + rsum;
      if (l16 == 0) Ab[16 * w + 4 * quad + i] = alpha_i;
    }
  };

  auto rescale = [&](const float* Ab) {
#pragma unroll
    for (int rt = 0; rt < 8; ++rt) {
      f32x4 ar = *(const f32x4*)&Ab[16 * rt + 4 * quad];
      bool nd = (ar[0] != 1.f) | (ar[1] != 1.f) | (ar[2] != 1.f) | (ar[3] != 1.f);
      if (__any(nd)) {
#pragma unroll
        for (int c2 = 0; c2 < 4; ++c2)
#pragma unroll
          for (int i = 0; i < 4; ++i) o[rt][c2][i] *= ar[i];
      }
    }
  };

  // PV from P buffer + vreg; reload vreg for m-offset mn as each pair is consumed
  half8 vreg[8];
  auto pv_step = [&](const _Float16* Pb, int mn) {
    __builtin_amdgcn_s_setprio(1);
#pragma unroll
    for (int rt = 0; rt < 8; ++rt) {
      half8 pa0 = *(const half8*)&Pb[(16 * rt + l16) * 72 + 8 * quad];
      half8 pa1 = *(const half8*)&Pb[(16 * rt + l16) * 72 + 32 + 8 * quad];
#pragma unroll
      for (int c2 = 0; c2 < 4; ++c2) {
        o[rt][c2] = __builtin_amdgcn_mfma_f32_16x16x32_f16(pa0, vreg[2 * c2], o[rt][c2], 0, 0, 0);
        o[rt][c2] = __builtin_amdgcn_mfma_f32_16x16x32_f16(pa1, vreg[2 * c2 + 1], o[rt][c2], 0, 0, 0);
      }
    }
    __builtin_amdgcn_s_setprio(0);
#pragma unroll
    for (int c2 = 0; c2 < 4; ++c2) {
      vreg[2 * c2]     = *(const half8*)&vp[c2 * 65536 + mn];
      vreg[2 * c2 + 1] = *(const half8*)&vp[c2 * 65536 + mn + 32];
    }
  };

  // ---- prologue: V(0) prefetch; K(0)->buf0, K(1)->buf1; QK(0)+softmax(0) ----
#pragma unroll
  for (int c2 = 0; c2 < 4; ++c2)
#pragma unroll
    for (int s = 0; s < 2; ++s)
      vreg[2 * c2 + s] = *(const half8*)&vp[c2 * 65536 + 32 * s];
  async_copy16(kbb + st_src, (char*)K_lds[0] + st_dst);
  async_copy16(kbb + 64 * 128 + st_src, (char*)K_lds[1] + st_dst);
  __syncthreads();
  qk_softmax(K_lds[0], P_lds[0], alpha_lds[0]);

#pragma unroll 1
  for (int it = 0; it < 63; ++it) {
    int cur = it & 1, nxt = cur ^ 1;
    __syncthreads();  // P(it)/alpha(it) visible; K(it+1) staged; PV(it-1) reads done
    int ms = (it + 2 < 64 ? it + 2 : 63) * 64;
    async_copy16(kbb + (size_t)ms * 128 + st_src, (char*)K_lds[cur] + st_dst);
    rescale(alpha_lds[cur]);
    if (pv_first) {
      pv_step(P_lds[cur], (it + 1) * 64);
      qk_softmax(K_lds[nxt], P_lds[nxt], alpha_lds[nxt]);
    } else {
      qk_softmax(K_lds[nxt], P_lds[nxt], alpha_lds[nxt]);
      pv_step(P_lds[cur], (it + 1) * 64);
    }
  }
  // ---- tail: iteration 63 ----
  __syncthreads();
  rescale(alpha_lds[1]);
  pv_step(P_lds[1], 63 * 64);

  // ---- finalize: reduce per-lane l partials, normalize, write ----
#pragma unroll
  for (int i = 0; i < 4; ++i) {
    float s = l_st[i];
#pragma unroll
    for (int off = 1; off < 16; off <<= 1) s += __shfl_xor(s, off);
    if (l16 == 0) l_lds[16 * w + 4 * quad + i] = s;
  }
  __syncthreads();
  float* ob = out + (size_t)b * 512 * 4096;
#pragma unroll
  for (int rt = 0; rt < 8; ++rt) {
    f32x4 lv = *(const f32x4*)&l_lds[16 * rt + 4 * quad];
    f32x4 inv;
#pragma unroll
    for (int i = 0; i < 4; ++i) inv[i] = 1.0f / lv[i];
#pragma unroll
    for (int c2 = 0; c2 < 4; ++c2) {
      int vv = 64 * w + 16 * c2 + l16;
      f32x4 res = o[rt][c2] * inv;
      *(f32x4*)(ob + (size_t)vv * 4096 + n0 + 16 * rt + 4 * quad) = res;
    }
  }
}

// ---------------- launch ----------------
extern "C" void kernel_launch(void* const* d_in, const int* in_sizes, int n_in,
                              void* d_out, int out_size, void* d_ws, size_t ws_size,
                              hipStream_t stream) {
  const float* x     = (const float*)d_in[0];
  const float* Wq    = (const float*)d_in[1];
  const float* bq    = (const float*)d_in[2];
  const float* Wk    = (const float*)d_in[3];
  const float* bk    = (const float*)d_in[4];
  const float* Wv    = (const float*)d_in[5];
  const float* gamma = (const float*)d_in[6];
  const float* beta  = (const float*)d_in[7];
  const float* mean  = (const float*)d_in[8];
  const float* var   = (const float*)d_in[9];
  float* out = (float*)d_out;

  char* ws = (char*)d_ws;
  _Float16* xT     = (_Float16*)(ws);                 // 33,554,432 B
  _Float16* W_all  = (_Float16*)(ws + 33554432);      //    655,360 B
  _Float16* q_buf  = (_Float16*)(ws + 34209792);      //  4,194,304 B
  _Float16* kT_buf = (_Float16*)(ws + 38404096);      //  4,194,304 B
  _Float16* v_buf  = (_Float16*)(ws + 42598400);      // 33,554,432 B -> total 76,152,832 B

  k_transpose<<<dim3(64, 8, 8), 256, 0, stream>>>(x, xT);
  k_wall<<<dim3(1280), 256, 0, stream>>>(Wq, Wk, Wv, W_all);
  k_proj<<<dim3(32, 5, 8), 256, 0, stream>>>(W_all, xT, bq, bk, gamma, beta, mean, var,
                                             q_buf, kT_buf, v_buf);
  k_flash<<<dim3(256), 512, 0, stream>>>(q_buf, kT_buf, v_buf, out);
}

// Round 6
// 388.404 us; speedup vs baseline: 1.0308x; 1.0308x over previous
//
#include <hip/hip_runtime.h>

typedef __attribute__((ext_vector_type(8))) _Float16 half8;
typedef __attribute__((ext_vector_type(4))) _Float16 half4;
typedef __attribute__((ext_vector_type(4))) float f32x4;

#define BN_EPS 1e-5f
#define LOG2E 1.4426950408889634f

__device__ __forceinline__ void async_copy16(const void* g, void* l) {
  __builtin_amdgcn_global_load_lds((const __attribute__((address_space(1))) void*)g,
                                   (__attribute__((address_space(3))) void*)l,
                                   16, 0, 0);
}

// ---------------- kernel 1: x (B,C,N) fp32 -> xT (B,N,C) fp16 ----------------
// Round-6: vectorized. float4 global loads (coalesced 256B rows), LDS transpose
// (65-pad: store-phase column reads are 2-way bank aliased = free), packed half4
// 8B global stores (coalesced 128B rows). Global side fully vectorized.
__global__ __launch_bounds__(256) void k_transpose(const float* __restrict__ x,
                                                   _Float16* __restrict__ xT) {
  __shared__ float tile[64][65];
  int n0 = blockIdx.x * 64, c0 = blockIdx.y * 64, b = blockIdx.z;
  const float* xb = x + (size_t)b * 512 * 4096;
  int t = threadIdx.x;
#pragma unroll
  for (int rep = 0; rep < 4; ++rep) {
    int f = rep * 256 + t;            // 0..1023 = 64 c-rows x 16 float4 chunks
    int c = f >> 4, n4 = f & 15;
    f32x4 v = *(const f32x4*)&xb[(size_t)(c0 + c) * 4096 + n0 + n4 * 4];
    tile[c][n4 * 4 + 0] = v[0];
    tile[c][n4 * 4 + 1] = v[1];
    tile[c][n4 * 4 + 2] = v[2];
    tile[c][n4 * 4 + 3] = v[3];
  }
  __syncthreads();
  _Float16* xTb = xT + (size_t)b * 4096 * 512;
#pragma unroll
  for (int rep = 0; rep < 4; ++rep) {
    int g = rep * 256 + t;            // 0..1023 = 64 n-rows x 16 half4 chunks
    int n = g >> 4, c4 = g & 15;
    half4 h;
#pragma unroll
    for (int j = 0; j < 4; ++j) h[j] = (_Float16)tile[c4 * 4 + j][n];
    *(half4*)&xTb[(size_t)(n0 + n) * 512 + c0 + c4 * 4] = h;
  }
}

// ---------------- kernel 2: W_all (640x512) fp16 = [Wq; Wk; Wv] ----------------
__global__ void k_wall(const float* __restrict__ Wq, const float* __restrict__ Wk,
                       const float* __restrict__ Wv, _Float16* __restrict__ W_all) {
  int i = blockIdx.x * 256 + threadIdx.x;
  if (i >= 640 * 512) return;
  int m = i >> 9, c = i & 511;
  float v;
  if (m < 64) v = Wq[m * 512 + c];
  else if (m < 128) v = Wk[(m - 64) * 512 + c];
  else v = Wv[(m - 128) * 512 + c];
  W_all[i] = (_Float16)v;
}

// ---------------- kernel 3: proj GEMM ----------------
// epilogue: q scaled by log2(e) so flash softmax can use native exp2.
// Round-6: double-buffered staging (T3-minimum). stage(kk+1) is issued BEFORE the
// compute of buf(kk), so the global_load_lds latency hides under the 16 MFMAs;
// one barrier per k-step (its vmcnt(0) drain lands after compute, not before).
__global__ __launch_bounds__(256) void k_proj(
    const _Float16* __restrict__ W_all, const _Float16* __restrict__ xT,
    const float* __restrict__ bq, const float* __restrict__ bk,
    const float* __restrict__ gamma, const float* __restrict__ beta,
    const float* __restrict__ mean, const float* __restrict__ var,
    _Float16* __restrict__ q_buf, _Float16* __restrict__ kT_buf,
    _Float16* __restrict__ v_buf) {
  __shared__ __align__(16) _Float16 A_lds[2][128 * 32];
  __shared__ __align__(16) _Float16 B_lds[2][128 * 32];
  int nt = blockIdx.x, mt = blockIdx.y, b = blockIdx.z;
  int t = threadIdx.x, w = t >> 6, lane = t & 63;
  int quad = lane >> 4, l16 = lane & 15;
  int moff = (w & 1) * 64, noff = (w >> 1) * 64;

  f32x4 acc[4][4] = {};

  auto stage = [&](int kk, int buf) {
    int kc = kk * 32;
#pragma unroll
    for (int c = 0; c < 2; ++c) {
      int row = (w * 2 + c) * 16 + (lane >> 2);
      int kseg = (lane & 3) * 8;
      async_copy16(W_all + (size_t)(mt * 128 + row) * 512 + kc + kseg,
                   (char*)A_lds[buf] + (w * 2 + c) * 1024 + lane * 16);
      async_copy16(xT + ((size_t)b * 4096 + nt * 128 + row) * 512 + kc + kseg,
                   (char*)B_lds[buf] + (w * 2 + c) * 1024 + lane * 16);
    }
  };

  stage(0, 0);
  __syncthreads();

#pragma unroll 1
  for (int kk = 0; kk < 16; ++kk) {
    int cur = kk & 1;
    if (kk < 15) stage(kk + 1, cur ^ 1);   // in flight during compute below
    half8 a[4], bb[4];
#pragma unroll
    for (int mi = 0; mi < 4; ++mi)
      a[mi] = *(const half8*)&A_lds[cur][(moff + 16 * mi + l16) * 32 + 8 * quad];
#pragma unroll
    for (int ni = 0; ni < 4; ++ni)
      bb[ni] = *(const half8*)&B_lds[cur][(noff + 16 * ni + l16) * 32 + 8 * quad];
#pragma unroll
    for (int mi = 0; mi < 4; ++mi)
#pragma unroll
      for (int ni = 0; ni < 4; ++ni)
        acc[mi][ni] = __builtin_amdgcn_mfma_f32_16x16x32_f16(a[mi], bb[ni], acc[mi][ni], 0, 0, 0);
    __syncthreads();  // drains stage(kk+1); protects buf(cur) for overwrite at kk+2
  }

  size_t bN = (size_t)b * 4096;
#pragma unroll
  for (int mi = 0; mi < 4; ++mi) {
    int mbase = mt * 128 + moff + 16 * mi + 4 * quad;
#pragma unroll
    for (int ni = 0; ni < 4; ++ni) {
      int n = nt * 128 + noff + 16 * ni + l16;
#pragma unroll
      for (int i = 0; i < 4; ++i) {
        int m = mbase + i;
        float val = acc[mi][ni][i];
        if (m < 64) {
          q_buf[(bN + n) * 64 + m] = (_Float16)((val + bq[m]) * LOG2E);
        } else if (m < 128) {
          kT_buf[(bN + n) * 64 + (m - 64)] = (_Float16)(val + bk[m - 64]);
        } else {
          int vv = m - 128;
          float sc = gamma[vv] * rsqrtf(var[vv] + BN_EPS);
          float sh = beta[vv] - mean[vv] * sc;
          float r = val * sc + sh;
          v_buf[((size_t)b * 512 + vv) * 4096 + n] = (_Float16)(r > 0.f ? r : 0.f);
        }
      }
    }
  }
}

// ---------------- kernel 4: flash attention, software-pipelined ----------------
// FROZEN this round (control). 256 blocks (bx&7 = batch -> XCD affinity, V 4MB/XCD
// in L2). 512 thr / 8 waves; wave w: S strip rows [16w,16w+16), O chunk V-cols
// [64w,64w+64). Pipeline: interval t does rescale(t) + PV(t) overlapped with
// QK(t+1)+softmax(t+1). One barrier/iter; P/alpha/K double-buffered; V prefetched
// in registers. Round-4: wave stagger (waves 4..7 PV-first) + s_setprio around
// MFMA clusters (262 -> 242 us). Round-5: defer-max THR=8 exact (242 -> 228 us).
__global__ __launch_bounds__(512, 2) void k_flash(
    const _Float16* __restrict__ q_buf, const _Float16* __restrict__ kT_buf,
    const _Float16* __restrict__ v_buf, float* __restrict__ out) {
  __shared__ __align__(16) _Float16 P_lds[2][128 * 72];
  __shared__ __align__(16) _Float16 K_lds[2][64 * 64];
  __shared__ __align__(16) float alpha_lds[2][128];
  __shared__ __align__(16) float l_lds[128];
  int bx = blockIdx.x;
  int b = bx & 7;
  int n0 = (bx >> 3) * 128;
  int t = threadIdx.x, w = t >> 6, lane = t & 63, quad = lane >> 4, l16 = lane & 15;
  const _Float16* qb = q_buf + (size_t)b * 4096 * 64;
  const char* kbb = (const char*)(kT_buf + (size_t)b * 4096 * 64);
  const _Float16* vp = v_buf + (size_t)b * 512 * 4096 + (size_t)(64 * w + l16) * 4096 + 8 * quad;

  bool pv_first = (w >= 4);  // wave-uniform; SIMD s hosts {s: qk-first, s+4: pv-first}

  int st_r = w * 8 + (lane >> 3);
  int st_c = (lane & 7) ^ (st_r & 7);
  int st_dst = w * 1024 + lane * 16;
  int st_src = st_r * 128 + st_c * 16;

  half8 aq[2];
#pragma unroll
  for (int s = 0; s < 2; ++s)
    aq[s] = *(const half8*)&qb[(size_t)(n0 + 16 * w + l16) * 64 + 32 * s + 8 * quad];

  f32x4 o[8][4] = {};
  float m_st[4], l_st[4];
#pragma unroll
  for (int i = 0; i < 4; ++i) { m_st[i] = -1e30f; l_st[i] = 0.f; }

  // QK(block) from K_lds buffer + online softmax -> P/alpha buffers, update m/l
  auto qk_softmax = [&](const _Float16* Kb, _Float16* Pb, float* Ab) {
    f32x4 sc[4];
    __builtin_amdgcn_s_setprio(1);
#pragma unroll
    for (int ct = 0; ct < 4; ++ct) {
      int row = 16 * ct + l16;
      int sw = (row & 7) * 16;
      half8 k0 = *(const half8*)((const char*)Kb + row * 128 + ((quad * 16) ^ sw));
      half8 k1 = *(const half8*)((const char*)Kb + row * 128 + (((4 + quad) * 16) ^ sw));
      f32x4 sa = {0.f, 0.f, 0.f, 0.f};
      sa = __builtin_amdgcn_mfma_f32_16x16x32_f16(aq[0], k0, sa, 0, 0, 0);
      sa = __builtin_amdgcn_mfma_f32_16x16x32_f16(aq[1], k1, sa, 0, 0, 0);
      sc[ct] = sa;
    }
    __builtin_amdgcn_s_setprio(0);
#pragma unroll
    for (int i = 0; i < 4; ++i) {
      float mxi = fmaxf(fmaxf(sc[0][i], sc[1][i]), fmaxf(sc[2][i], sc[3][i]));
#pragma unroll
      for (int off = 1; off < 16; off <<= 1) mxi = fmaxf(mxi, __shfl_xor(mxi, off));
      float mnew = (mxi > m_st[i] + 8.f) ? mxi : m_st[i];  // defer-max (exact)
      float alpha_i = exp2f(m_st[i] - mnew);
      m_st[i] = mnew;
      float rsum = 0.f;
#pragma unroll
      for (int ct = 0; ct < 4; ++ct) {
        float pv = exp2f(sc[ct][i] - mnew);
        Pb[(16 * w + 4 * quad + i) * 72 + 16 * ct + l16] = (_Float16)pv;
        rsum += pv;
      }
      l_st[i] = l_st[i] * alpha_i + rsum;
      if (l16 == 0) Ab[16 * w + 4 * quad + i] = alpha_i;
    }
  };

  auto rescale = [&](const float* Ab) {
#pragma unroll
    for (int rt = 0; rt < 8; ++rt) {
      f32x4 ar = *(const f32x4*)&Ab[16 * rt + 4 * quad];
      bool nd = (ar[0] != 1.f) | (ar[1] != 1.f) | (ar[2] != 1.f) | (ar[3] != 1.f);
      if (__any(nd)) {
#pragma unroll
        for (int c2 = 0; c2 < 4; ++c2)
#pragma unroll
          for (int i = 0; i < 4; ++i) o[rt][c2][i] *= ar[i];
      }
    }
  };

  // PV from P buffer + vreg; reload vreg for m-offset mn as each pair is consumed
  half8 vreg[8];
  auto pv_step = [&](const _Float16* Pb, int mn) {
    __builtin_amdgcn_s_setprio(1);
#pragma unroll
    for (int rt = 0; rt < 8; ++rt) {
      half8 pa0 = *(const half8*)&Pb[(16 * rt + l16) * 72 + 8 * quad];
      half8 pa1 = *(const half8*)&Pb[(16 * rt + l16) * 72 + 32 + 8 * quad];
#pragma unroll
      for (int c2 = 0; c2 < 4; ++c2) {
        o[rt][c2] = __builtin_amdgcn_mfma_f32_16x16x32_f16(pa0, vreg[2 * c2], o[rt][c2], 0, 0, 0);
        o[rt][c2] = __builtin_amdgcn_mfma_f32_16x16x32_f16(pa1, vreg[2 * c2 + 1], o[rt][c2], 0, 0, 0);
      }
    }
    __builtin_amdgcn_s_setprio(0);
#pragma unroll
    for (int c2 = 0; c2 < 4; ++c2) {
      vreg[2 * c2]     = *(const half8*)&vp[c2 * 65536 + mn];
      vreg[2 * c2 + 1] = *(const half8*)&vp[c2 * 65536 + mn + 32];
    }
  };

  // ---- prologue: V(0) prefetch; K(0)->buf0, K(1)->buf1; QK(0)+softmax(0) ----
#pragma unroll
  for (int c2 = 0; c2 < 4; ++c2)
#pragma unroll
    for (int s = 0; s < 2; ++s)
      vreg[2 * c2 + s] = *(const half8*)&vp[c2 * 65536 + 32 * s];
  async_copy16(kbb + st_src, (char*)K_lds[0] + st_dst);
  async_copy16(kbb + 64 * 128 + st_src, (char*)K_lds[1] + st_dst);
  __syncthreads();
  qk_softmax(K_lds[0], P_lds[0], alpha_lds[0]);

#pragma unroll 1
  for (int it = 0; it < 63; ++it) {
    int cur = it & 1, nxt = cur ^ 1;
    __syncthreads();  // P(it)/alpha(it) visible; K(it+1) staged; PV(it-1) reads done
    int ms = (it + 2 < 64 ? it + 2 : 63) * 64;
    async_copy16(kbb + (size_t)ms * 128 + st_src, (char*)K_lds[cur] + st_dst);
    rescale(alpha_lds[cur]);
    if (pv_first) {
      pv_step(P_lds[cur], (it + 1) * 64);
      qk_softmax(K_lds[nxt], P_lds[nxt], alpha_lds[nxt]);
    } else {
      qk_softmax(K_lds[nxt], P_lds[nxt], alpha_lds[nxt]);
      pv_step(P_lds[cur], (it + 1) * 64);
    }
  }
  // ---- tail: iteration 63 ----
  __syncthreads();
  rescale(alpha_lds[1]);
  pv_step(P_lds[1], 63 * 64);

  // ---- finalize: reduce per-lane l partials, normalize, write ----
#pragma unroll
  for (int i = 0; i < 4; ++i) {
    float s = l_st[i];
#pragma unroll
    for (int off = 1; off < 16; off <<= 1) s += __shfl_xor(s, off);
    if (l16 == 0) l_lds[16 * w + 4 * quad + i] = s;
  }
  __syncthreads();
  float* ob = out + (size_t)b * 512 * 4096;
#pragma unroll
  for (int rt = 0; rt < 8; ++rt) {
    f32x4 lv = *(const f32x4*)&l_lds[16 * rt + 4 * quad];
    f32x4 inv;
#pragma unroll
    for (int i = 0; i < 4; ++i) inv[i] = 1.0f / lv[i];
#pragma unroll
    for (int c2 = 0; c2 < 4; ++c2) {
      int vv = 64 * w + 16 * c2 + l16;
      f32x4 res = o[rt][c2] * inv;
      *(f32x4*)(ob + (size_t)vv * 4096 + n0 + 16 * rt + 4 * quad) = res;
    }
  }
}

// ---------------- launch ----------------
extern "C" void kernel_launch(void* const* d_in, const int* in_sizes, int n_in,
                              void* d_out, int out_size, void* d_ws, size_t ws_size,
                              hipStream_t stream) {
  const float* x     = (const float*)d_in[0];
  const float* Wq    = (const float*)d_in[1];
  const float* bq    = (const float*)d_in[2];
  const float* Wk    = (const float*)d_in[3];
  const float* bk    = (const float*)d_in[4];
  const float* Wv    = (const float*)d_in[5];
  const float* gamma = (const float*)d_in[6];
  const float* beta  = (const float*)d_in[7];
  const float* mean  = (const float*)d_in[8];
  const float* var   = (const float*)d_in[9];
  float* out = (float*)d_out;

  char* ws = (char*)d_ws;
  _Float16* xT     = (_Float16*)(ws);                 // 33,554,432 B
  _Float16* W_all  = (_Float16*)(ws + 33554432);      //    655,360 B
  _Float16* q_buf  = (_Float16*)(ws + 34209792);      //  4,194,304 B
  _Float16* kT_buf = (_Float16*)(ws + 38404096);      //  4,194,304 B
  _Float16* v_buf  = (_Float16*)(ws + 42598400);      // 33,554,432 B -> total 76,152,832 B

  k_transpose<<<dim3(64, 8, 8), 256, 0, stream>>>(x, xT);
  k_wall<<<dim3(1280), 256, 0, stream>>>(Wq, Wk, Wv, W_all);
  k_proj<<<dim3(32, 5, 8), 256, 0, stream>>>(W_all, xT, bq, bk, gamma, beta, mean, var,
                                             q_buf, kT_buf, v_buf);
  k_flash<<<dim3(256), 512, 0, stream>>>(q_buf, kT_buf, v_buf, out);
}

// Round 7
// 369.710 us; speedup vs baseline: 1.0829x; 1.0506x over previous
//
#include <hip/hip_runtime.h>

typedef __attribute__((ext_vector_type(8))) _Float16 half8;
typedef __attribute__((ext_vector_type(4))) _Float16 half4;
typedef __attribute__((ext_vector_type(4))) float f32x4;

#define BN_EPS 1e-5f
#define LOG2E 1.4426950408889634f

__device__ __forceinline__ void async_copy16(const void* g, void* l) {
  __builtin_amdgcn_global_load_lds((const __attribute__((address_space(1))) void*)g,
                                   (__attribute__((address_space(3))) void*)l,
                                   16, 0, 0);
}

// ---------------- kernel 1: x (B,C,N) fp32 -> xT (B,N,C) fp16 ----------------
// Round-6: vectorized. float4 global loads (coalesced 256B rows), LDS transpose
// (65-pad), packed half4 8B global stores (coalesced 128B rows).
__global__ __launch_bounds__(256) void k_transpose(const float* __restrict__ x,
                                                   _Float16* __restrict__ xT) {
  __shared__ float tile[64][65];
  int n0 = blockIdx.x * 64, c0 = blockIdx.y * 64, b = blockIdx.z;
  const float* xb = x + (size_t)b * 512 * 4096;
  int t = threadIdx.x;
#pragma unroll
  for (int rep = 0; rep < 4; ++rep) {
    int f = rep * 256 + t;            // 0..1023 = 64 c-rows x 16 float4 chunks
    int c = f >> 4, n4 = f & 15;
    f32x4 v = *(const f32x4*)&xb[(size_t)(c0 + c) * 4096 + n0 + n4 * 4];
    tile[c][n4 * 4 + 0] = v[0];
    tile[c][n4 * 4 + 1] = v[1];
    tile[c][n4 * 4 + 2] = v[2];
    tile[c][n4 * 4 + 3] = v[3];
  }
  __syncthreads();
  _Float16* xTb = xT + (size_t)b * 4096 * 512;
#pragma unroll
  for (int rep = 0; rep < 4; ++rep) {
    int g = rep * 256 + t;            // 0..1023 = 64 n-rows x 16 half4 chunks
    int n = g >> 4, c4 = g & 15;
    half4 h;
#pragma unroll
    for (int j = 0; j < 4; ++j) h[j] = (_Float16)tile[c4 * 4 + j][n];
    *(half4*)&xTb[(size_t)(n0 + n) * 512 + c0 + c4 * 4] = h;
  }
}

// ---------------- kernel 2: W_all (640x512) fp16 = [Wq; Wk; Wv] ----------------
__global__ void k_wall(const float* __restrict__ Wq, const float* __restrict__ Wk,
                       const float* __restrict__ Wv, _Float16* __restrict__ W_all) {
  int i = blockIdx.x * 256 + threadIdx.x;
  if (i >= 640 * 512) return;
  int m = i >> 9, c = i & 511;
  float v;
  if (m < 64) v = Wq[m * 512 + c];
  else if (m < 128) v = Wk[(m - 64) * 512 + c];
  else v = Wv[(m - 128) * 512 + c];
  W_all[i] = (_Float16)v;
}

// ---------------- kernel 3: proj GEMM ----------------
// epilogue: q scaled by log2(e) so flash softmax can use native exp2.
// Round-6: double-buffered staging (T3-minimum); stage(kk+1) issued before
// compute of buf(kk) so global_load_lds latency hides under the 16 MFMAs.
__global__ __launch_bounds__(256) void k_proj(
    const _Float16* __restrict__ W_all, const _Float16* __restrict__ xT,
    const float* __restrict__ bq, const float* __restrict__ bk,
    const float* __restrict__ gamma, const float* __restrict__ beta,
    const float* __restrict__ mean, const float* __restrict__ var,
    _Float16* __restrict__ q_buf, _Float16* __restrict__ kT_buf,
    _Float16* __restrict__ v_buf) {
  __shared__ __align__(16) _Float16 A_lds[2][128 * 32];
  __shared__ __align__(16) _Float16 B_lds[2][128 * 32];
  int nt = blockIdx.x, mt = blockIdx.y, b = blockIdx.z;
  int t = threadIdx.x, w = t >> 6, lane = t & 63;
  int quad = lane >> 4, l16 = lane & 15;
  int moff = (w & 1) * 64, noff = (w >> 1) * 64;

  f32x4 acc[4][4] = {};

  auto stage = [&](int kk, int buf) {
    int kc = kk * 32;
#pragma unroll
    for (int c = 0; c < 2; ++c) {
      int row = (w * 2 + c) * 16 + (lane >> 2);
      int kseg = (lane & 3) * 8;
      async_copy16(W_all + (size_t)(mt * 128 + row) * 512 + kc + kseg,
                   (char*)A_lds[buf] + (w * 2 + c) * 1024 + lane * 16);
      async_copy16(xT + ((size_t)b * 4096 + nt * 128 + row) * 512 + kc + kseg,
                   (char*)B_lds[buf] + (w * 2 + c) * 1024 + lane * 16);
    }
  };

  stage(0, 0);
  __syncthreads();

#pragma unroll 1
  for (int kk = 0; kk < 16; ++kk) {
    int cur = kk & 1;
    if (kk < 15) stage(kk + 1, cur ^ 1);   // in flight during compute below
    half8 a[4], bb[4];
#pragma unroll
    for (int mi = 0; mi < 4; ++mi)
      a[mi] = *(const half8*)&A_lds[cur][(moff + 16 * mi + l16) * 32 + 8 * quad];
#pragma unroll
    for (int ni = 0; ni < 4; ++ni)
      bb[ni] = *(const half8*)&B_lds[cur][(noff + 16 * ni + l16) * 32 + 8 * quad];
#pragma unroll
    for (int mi = 0; mi < 4; ++mi)
#pragma unroll
      for (int ni = 0; ni < 4; ++ni)
        acc[mi][ni] = __builtin_amdgcn_mfma_f32_16x16x32_f16(a[mi], bb[ni], acc[mi][ni], 0, 0, 0);
    __syncthreads();  // drains stage(kk+1); protects buf(cur) for overwrite at kk+2
  }

  size_t bN = (size_t)b * 4096;
#pragma unroll
  for (int mi = 0; mi < 4; ++mi) {
    int mbase = mt * 128 + moff + 16 * mi + 4 * quad;
#pragma unroll
    for (int ni = 0; ni < 4; ++ni) {
      int n = nt * 128 + noff + 16 * ni + l16;
#pragma unroll
      for (int i = 0; i < 4; ++i) {
        int m = mbase + i;
        float val = acc[mi][ni][i];
        if (m < 64) {
          q_buf[(bN + n) * 64 + m] = (_Float16)((val + bq[m]) * LOG2E);
        } else if (m < 128) {
          kT_buf[(bN + n) * 64 + (m - 64)] = (_Float16)(val + bk[m - 64]);
        } else {
          int vv = m - 128;
          float sc = gamma[vv] * rsqrtf(var[vv] + BN_EPS);
          float sh = beta[vv] - mean[vv] * sc;
          float r = val * sc + sh;
          v_buf[((size_t)b * 512 + vv) * 4096 + n] = (_Float16)(r > 0.f ? r : 0.f);
        }
      }
    }
  }
}

// ---------------- kernel 4: flash attention, software-pipelined ----------------
// 256 blocks (bx&7 = batch -> XCD affinity, V 4MB/XCD in L2). 512 thr / 8 waves;
// wave w: S strip rows [16w,16w+16), O chunk V-cols [64w,64w+64). Pipeline:
// interval t does rescale(t) + PV(t) overlapped with QK(t+1)+softmax(t+1).
// One barrier/iter; P/alpha/K double-buffered; V prefetched in registers.
// Round-4: wave stagger + s_setprio (262 -> 242). Round-5: defer-max THR=8
// (242 -> 228). Round-7: BALLOT-GATED max reduce — the 4-hop serial __shfl_xor
// row-max (and the alpha exp2) run only when __any lane's local max threatens
// m+8; common path is 3 fmax + 1 cmp + ballot. Same defer-max semantics: m is
// raised only from the group-uniform reduced max, so m stays uniform per
// 16-lane group; P <= 2^8 (fp16-safe).
__global__ __launch_bounds__(512, 2) void k_flash(
    const _Float16* __restrict__ q_buf, const _Float16* __restrict__ kT_buf,
    const _Float16* __restrict__ v_buf, float* __restrict__ out) {
  __shared__ __align__(16) _Float16 P_lds[2][128 * 72];
  __shared__ __align__(16) _Float16 K_lds[2][64 * 64];
  __shared__ __align__(16) float alpha_lds[2][128];
  __shared__ __align__(16) float l_lds[128];
  int bx = blockIdx.x;
  int b = bx & 7;
  int n0 = (bx >> 3) * 128;
  int t = threadIdx.x, w = t >> 6, lane = t & 63, quad = lane >> 4, l16 = lane & 15;
  const _Float16* qb = q_buf + (size_t)b * 4096 * 64;
  const char* kbb = (const char*)(kT_buf + (size_t)b * 4096 * 64);
  const _Float16* vp = v_buf + (size_t)b * 512 * 4096 + (size_t)(64 * w + l16) * 4096 + 8 * quad;

  bool pv_first = (w >= 4);  // wave-uniform; SIMD s hosts {s: qk-first, s+4: pv-first}

  int st_r = w * 8 + (lane >> 3);
  int st_c = (lane & 7) ^ (st_r & 7);
  int st_dst = w * 1024 + lane * 16;
  int st_src = st_r * 128 + st_c * 16;

  half8 aq[2];
#pragma unroll
  for (int s = 0; s < 2; ++s)
    aq[s] = *(const half8*)&qb[(size_t)(n0 + 16 * w + l16) * 64 + 32 * s + 8 * quad];

  f32x4 o[8][4] = {};
  float m_st[4], l_st[4];
#pragma unroll
  for (int i = 0; i < 4; ++i) { m_st[i] = -1e30f; l_st[i] = 0.f; }

  // QK(block) from K_lds buffer + online softmax -> P/alpha buffers, update m/l
  auto qk_softmax = [&](const _Float16* Kb, _Float16* Pb, float* Ab) {
    f32x4 sc[4];
    __builtin_amdgcn_s_setprio(1);
#pragma unroll
    for (int ct = 0; ct < 4; ++ct) {
      int row = 16 * ct + l16;
      int sw = (row & 7) * 16;
      half8 k0 = *(const half8*)((const char*)Kb + row * 128 + ((quad * 16) ^ sw));
      half8 k1 = *(const half8*)((const char*)Kb + row * 128 + (((4 + quad) * 16) ^ sw));
      f32x4 sa = {0.f, 0.f, 0.f, 0.f};
      sa = __builtin_amdgcn_mfma_f32_16x16x32_f16(aq[0], k0, sa, 0, 0, 0);
      sa = __builtin_amdgcn_mfma_f32_16x16x32_f16(aq[1], k1, sa, 0, 0, 0);
      sc[ct] = sa;
    }
    __builtin_amdgcn_s_setprio(0);
#pragma unroll
    for (int i = 0; i < 4; ++i) {
      float lmax = fmaxf(fmaxf(sc[0][i], sc[1][i]), fmaxf(sc[2][i], sc[3][i]));
      float alpha_i = 1.f;
      if (__any(lmax > m_st[i] + 8.f)) {     // rare: full reduce + possible raise
        float mxi = lmax;
#pragma unroll
        for (int off = 1; off < 16; off <<= 1) mxi = fmaxf(mxi, __shfl_xor(mxi, off));
        if (mxi > m_st[i] + 8.f) {           // group-uniform decision
          alpha_i = exp2f(m_st[i] - mxi);
          m_st[i] = mxi;
        }
      }
      float rsum = 0.f;
#pragma unroll
      for (int ct = 0; ct < 4; ++ct) {
        float pv = exp2f(sc[ct][i] - m_st[i]);
        Pb[(16 * w + 4 * quad + i) * 72 + 16 * ct + l16] = (_Float16)pv;
        rsum += pv;
      }
      l_st[i] = l_st[i] * alpha_i + rsum;
      if (l16 == 0) Ab[16 * w + 4 * quad + i] = alpha_i;
    }
  };

  auto rescale = [&](const float* Ab) {
#pragma unroll
    for (int rt = 0; rt < 8; ++rt) {
      f32x4 ar = *(const f32x4*)&Ab[16 * rt + 4 * quad];
      bool nd = (ar[0] != 1.f) | (ar[1] != 1.f) | (ar[2] != 1.f) | (ar[3] != 1.f);
      if (__any(nd)) {
#pragma unroll
        for (int c2 = 0; c2 < 4; ++c2)
#pragma unroll
          for (int i = 0; i < 4; ++i) o[rt][c2][i] *= ar[i];
      }
    }
  };

  // PV from P buffer + vreg; reload vreg for m-offset mn as each pair is consumed
  half8 vreg[8];
  auto pv_step = [&](const _Float16* Pb, int mn) {
    __builtin_amdgcn_s_setprio(1);
#pragma unroll
    for (int rt = 0; rt < 8; ++rt) {
      half8 pa0 = *(const half8*)&Pb[(16 * rt + l16) * 72 + 8 * quad];
      half8 pa1 = *(const half8*)&Pb[(16 * rt + l16) * 72 + 32 + 8 * quad];
#pragma unroll
      for (int c2 = 0; c2 < 4; ++c2) {
        o[rt][c2] = __builtin_amdgcn_mfma_f32_16x16x32_f16(pa0, vreg[2 * c2], o[rt][c2], 0, 0, 0);
        o[rt][c2] = __builtin_amdgcn_mfma_f32_16x16x32_f16(pa1, vreg[2 * c2 + 1], o[rt][c2], 0, 0, 0);
      }
    }
    __builtin_amdgcn_s_setprio(0);
#pragma unroll
    for (int c2 = 0; c2 < 4; ++c2) {
      vreg[2 * c2]     = *(const half8*)&vp[c2 * 65536 + mn];
      vreg[2 * c2 + 1] = *(const half8*)&vp[c2 * 65536 + mn + 32];
    }
  };

  // ---- prologue: V(0) prefetch; K(0)->buf0, K(1)->buf1; QK(0)+softmax(0) ----
#pragma unroll
  for (int c2 = 0; c2 < 4; ++c2)
#pragma unroll
    for (int s = 0; s < 2; ++s)
      vreg[2 * c2 + s] = *(const half8*)&vp[c2 * 65536 + 32 * s];
  async_copy16(kbb + st_src, (char*)K_lds[0] + st_dst);
  async_copy16(kbb + 64 * 128 + st_src, (char*)K_lds[1] + st_dst);
  __syncthreads();
  qk_softmax(K_lds[0], P_lds[0], alpha_lds[0]);

#pragma unroll 1
  for (int it = 0; it < 63; ++it) {
    int cur = it & 1, nxt = cur ^ 1;
    __syncthreads();  // P(it)/alpha(it) visible; K(it+1) staged; PV(it-1) reads done
    int ms = (it + 2 < 64 ? it + 2 : 63) * 64;
    async_copy16(kbb + (size_t)ms * 128 + st_src, (char*)K_lds[cur] + st_dst);
    rescale(alpha_lds[cur]);
    if (pv_first) {
      pv_step(P_lds[cur], (it + 1) * 64);
      qk_softmax(K_lds[nxt], P_lds[nxt], alpha_lds[nxt]);
    } else {
      qk_softmax(K_lds[nxt], P_lds[nxt], alpha_lds[nxt]);
      pv_step(P_lds[cur], (it + 1) * 64);
    }
  }
  // ---- tail: iteration 63 ----
  __syncthreads();
  rescale(alpha_lds[1]);
  pv_step(P_lds[1], 63 * 64);

  // ---- finalize: reduce per-lane l partials, normalize, write ----
#pragma unroll
  for (int i = 0; i < 4; ++i) {
    float s = l_st[i];
#pragma unroll
    for (int off = 1; off < 16; off <<= 1) s += __shfl_xor(s, off);
    if (l16 == 0) l_lds[16 * w + 4 * quad + i] = s;
  }
  __syncthreads();
  float* ob = out + (size_t)b * 512 * 4096;
#pragma unroll
  for (int rt = 0; rt < 8; ++rt) {
    f32x4 lv = *(const f32x4*)&l_lds[16 * rt + 4 * quad];
    f32x4 inv;
#pragma unroll
    for (int i = 0; i < 4; ++i) inv[i] = 1.0f / lv[i];
#pragma unroll
    for (int c2 = 0; c2 < 4; ++c2) {
      int vv = 64 * w + 16 * c2 + l16;
      f32x4 res = o[rt][c2] * inv;
      *(f32x4*)(ob + (size_t)vv * 4096 + n0 + 16 * rt + 4 * quad) = res;
    }
  }
}

// ---------------- launch ----------------
extern "C" void kernel_launch(void* const* d_in, const int* in_sizes, int n_in,
                              void* d_out, int out_size, void* d_ws, size_t ws_size,
                              hipStream_t stream) {
  const float* x     = (const float*)d_in[0];
  const float* Wq    = (const float*)d_in[1];
  const float* bq    = (const float*)d_in[2];
  const float* Wk    = (const float*)d_in[3];
  const float* bk    = (const float*)d_in[4];
  const float* Wv    = (const float*)d_in[5];
  const float* gamma = (const float*)d_in[6];
  const float* beta  = (const float*)d_in[7];
  const float* mean  = (const float*)d_in[8];
  const float* var   = (const float*)d_in[9];
  float* out = (float*)d_out;

  char* ws = (char*)d_ws;
  _Float16* xT     = (_Float16*)(ws);                 // 33,554,432 B
  _Float16* W_all  = (_Float16*)(ws + 33554432);      //    655,360 B
  _Float16* q_buf  = (_Float16*)(ws + 34209792);      //  4,194,304 B
  _Float16* kT_buf = (_Float16*)(ws + 38404096);      //  4,194,304 B
  _Float16* v_buf  = (_Float16*)(ws + 42598400);      // 33,554,432 B -> total 76,152,832 B

  k_transpose<<<dim3(64, 8, 8), 256, 0, stream>>>(x, xT);
  k_wall<<<dim3(1280), 256, 0, stream>>>(Wq, Wk, Wv, W_all);
  k_proj<<<dim3(32, 5, 8), 256, 0, stream>>>(W_all, xT, bq, bk, gamma, beta, mean, var,
                                             q_buf, kT_buf, v_buf);
  k_flash<<<dim3(256), 512, 0, stream>>>(q_buf, kT_buf, v_buf, out);
}

// Round 9
// 356.218 us; speedup vs baseline: 1.1239x; 1.0379x over previous
//
#include <hip/hip_runtime.h>

typedef __attribute__((ext_vector_type(8))) _Float16 half8;
typedef __attribute__((ext_vector_type(4))) _Float16 half4;
typedef __attribute__((ext_vector_type(4))) float f32x4;

#define BN_EPS 1e-5f
#define LOG2E 1.4426950408889634f

__device__ __forceinline__ void async_copy16(const void* g, void* l) {
  __builtin_amdgcn_global_load_lds((const __attribute__((address_space(1))) void*)g,
                                   (__attribute__((address_space(3))) void*)l,
                                   16, 0, 0);
}

// ---------------- kernel 1: x (B,C,N) fp32 -> xT (B,N,C) fp16 ----------------
// Round-6: vectorized. float4 global loads (coalesced 256B rows), LDS transpose
// (65-pad), packed half4 8B global stores (coalesced 128B rows).
__global__ __launch_bounds__(256) void k_transpose(const float* __restrict__ x,
                                                   _Float16* __restrict__ xT) {
  __shared__ float tile[64][65];
  int n0 = blockIdx.x * 64, c0 = blockIdx.y * 64, b = blockIdx.z;
  const float* xb = x + (size_t)b * 512 * 4096;
  int t = threadIdx.x;
#pragma unroll
  for (int rep = 0; rep < 4; ++rep) {
    int f = rep * 256 + t;            // 0..1023 = 64 c-rows x 16 float4 chunks
    int c = f >> 4, n4 = f & 15;
    f32x4 v = *(const f32x4*)&xb[(size_t)(c0 + c) * 4096 + n0 + n4 * 4];
    tile[c][n4 * 4 + 0] = v[0];
    tile[c][n4 * 4 + 1] = v[1];
    tile[c][n4 * 4 + 2] = v[2];
    tile[c][n4 * 4 + 3] = v[3];
  }
  __syncthreads();
  _Float16* xTb = xT + (size_t)b * 4096 * 512;
#pragma unroll
  for (int rep = 0; rep < 4; ++rep) {
    int g = rep * 256 + t;            // 0..1023 = 64 n-rows x 16 half4 chunks
    int n = g >> 4, c4 = g & 15;
    half4 h;
#pragma unroll
    for (int j = 0; j < 4; ++j) h[j] = (_Float16)tile[c4 * 4 + j][n];
    *(half4*)&xTb[(size_t)(n0 + n) * 512 + c0 + c4 * 4] = h;
  }
}

// ---------------- kernel 2: W_all (640x512) fp16 = [Wq; Wk; Wv] ----------------
__global__ void k_wall(const float* __restrict__ Wq, const float* __restrict__ Wk,
                       const float* __restrict__ Wv, _Float16* __restrict__ W_all) {
  int i = blockIdx.x * 256 + threadIdx.x;
  if (i >= 640 * 512) return;
  int m = i >> 9, c = i & 511;
  float v;
  if (m < 64) v = Wq[m * 512 + c];
  else if (m < 128) v = Wk[(m - 64) * 512 + c];
  else v = Wv[(m - 128) * 512 + c];
  W_all[i] = (_Float16)v;
}

// ---------------- kernel 3: proj GEMM ----------------
// epilogue: q scaled by log2(e) so flash softmax can use native exp2.
// Round-6: double-buffered staging (T3-minimum). Round-8: q/kT epilogue stores
// packed half4 (mbase+i are 4 consecutive m for fixed n; 8B-aligned).
__global__ __launch_bounds__(256) void k_proj(
    const _Float16* __restrict__ W_all, const _Float16* __restrict__ xT,
    const float* __restrict__ bq, const float* __restrict__ bk,
    const float* __restrict__ gamma, const float* __restrict__ beta,
    const float* __restrict__ mean, const float* __restrict__ var,
    _Float16* __restrict__ q_buf, _Float16* __restrict__ kT_buf,
    _Float16* __restrict__ v_buf) {
  __shared__ __align__(16) _Float16 A_lds[2][128 * 32];
  __shared__ __align__(16) _Float16 B_lds[2][128 * 32];
  int nt = blockIdx.x, mt = blockIdx.y, b = blockIdx.z;
  int t = threadIdx.x, w = t >> 6, lane = t & 63;
  int quad = lane >> 4, l16 = lane & 15;
  int moff = (w & 1) * 64, noff = (w >> 1) * 64;

  f32x4 acc[4][4] = {};

  auto stage = [&](int kk, int buf) {
    int kc = kk * 32;
#pragma unroll
    for (int c = 0; c < 2; ++c) {
      int row = (w * 2 + c) * 16 + (lane >> 2);
      int kseg = (lane & 3) * 8;
      async_copy16(W_all + (size_t)(mt * 128 + row) * 512 + kc + kseg,
                   (char*)A_lds[buf] + (w * 2 + c) * 1024 + lane * 16);
      async_copy16(xT + ((size_t)b * 4096 + nt * 128 + row) * 512 + kc + kseg,
                   (char*)B_lds[buf] + (w * 2 + c) * 1024 + lane * 16);
    }
  };

  stage(0, 0);
  __syncthreads();

#pragma unroll 1
  for (int kk = 0; kk < 16; ++kk) {
    int cur = kk & 1;
    if (kk < 15) stage(kk + 1, cur ^ 1);   // in flight during compute below
    half8 a[4], bb[4];
#pragma unroll
    for (int mi = 0; mi < 4; ++mi)
      a[mi] = *(const half8*)&A_lds[cur][(moff + 16 * mi + l16) * 32 + 8 * quad];
#pragma unroll
    for (int ni = 0; ni < 4; ++ni)
      bb[ni] = *(const half8*)&B_lds[cur][(noff + 16 * ni + l16) * 32 + 8 * quad];
#pragma unroll
    for (int mi = 0; mi < 4; ++mi)
#pragma unroll
      for (int ni = 0; ni < 4; ++ni)
        acc[mi][ni] = __builtin_amdgcn_mfma_f32_16x16x32_f16(a[mi], bb[ni], acc[mi][ni], 0, 0, 0);
    __syncthreads();  // drains stage(kk+1); protects buf(cur) for overwrite at kk+2
  }

  size_t bN = (size_t)b * 4096;
#pragma unroll
  for (int mi = 0; mi < 4; ++mi) {
    int mbase = mt * 128 + moff + 16 * mi + 4 * quad;
#pragma unroll
    for (int ni = 0; ni < 4; ++ni) {
      int n = nt * 128 + noff + 16 * ni + l16;
      if (mbase < 64) {
        half4 h;
#pragma unroll
        for (int i = 0; i < 4; ++i)
          h[i] = (_Float16)((acc[mi][ni][i] + bq[mbase + i]) * LOG2E);
        *(half4*)&q_buf[(bN + n) * 64 + mbase] = h;
      } else if (mbase < 128) {
        half4 h;
#pragma unroll
        for (int i = 0; i < 4; ++i)
          h[i] = (_Float16)(acc[mi][ni][i] + bk[mbase - 64 + i]);
        *(half4*)&kT_buf[(bN + n) * 64 + (mbase - 64)] = h;
      } else {
#pragma unroll
        for (int i = 0; i < 4; ++i) {
          int vv = mbase - 128 + i;
          float sc = gamma[vv] * rsqrtf(var[vv] + BN_EPS);
          float sh = beta[vv] - mean[vv] * sc;
          float r = acc[mi][ni][i] * sc + sh;
          v_buf[((size_t)b * 512 + vv) * 4096 + n] = (_Float16)(r > 0.f ? r : 0.f);
        }
      }
    }
  }
}

// ---------------- kernel 4: flash attention, software-pipelined ----------------
// 256 blocks (bx&7 = batch -> XCD affinity, V 4MB/XCD in L2). 512 thr / 8 waves;
// wave w: S strip rows [16w,16w+16), O chunk V-cols [64w,64w+64). Pipeline:
// interval t does rescale(t) + PV(t) overlapped with QK(t+1)+softmax(t+1).
// One barrier/iter; P/alpha/K double-buffered; V prefetched in registers.
// R4: wave stagger + s_setprio (262 -> 242). R5: defer-max THR=8 (242 -> 228).
// R7: ballot-gated max reduce (228 -> 209). R8: PER-STRIP RAISED FLAGS —
// qk_softmax writes alpha + flag byte only when its strip raised m; rescale
// reads one b64 of flags (wave-uniform) and skips everything when zero;
// raised strips multiply unconditionally (x1.0 rows harmless). Exact math.
__global__ __launch_bounds__(512, 2) void k_flash(
    const _Float16* __restrict__ q_buf, const _Float16* __restrict__ kT_buf,
    const _Float16* __restrict__ v_buf, float* __restrict__ out) {
  __shared__ __align__(16) _Float16 P_lds[2][128 * 72];
  __shared__ __align__(16) _Float16 K_lds[2][64 * 64];
  __shared__ __align__(16) float alpha_lds[2][128];
  __shared__ __align__(8) unsigned char aflag[2][8];
  __shared__ __align__(16) float l_lds[128];
  int bx = blockIdx.x;
  int b = bx & 7;
  int n0 = (bx >> 3) * 128;
  int t = threadIdx.x, w = t >> 6, lane = t & 63, quad = lane >> 4, l16 = lane & 15;
  const _Float16* qb = q_buf + (size_t)b * 4096 * 64;
  const char* kbb = (const char*)(kT_buf + (size_t)b * 4096 * 64);
  const _Float16* vp = v_buf + (size_t)b * 512 * 4096 + (size_t)(64 * w + l16) * 4096 + 8 * quad;

  bool pv_first = (w >= 4);  // wave-uniform; SIMD s hosts {s: qk-first, s+4: pv-first}

  int st_r = w * 8 + (lane >> 3);
  int st_c = (lane & 7) ^ (st_r & 7);
  int st_dst = w * 1024 + lane * 16;
  int st_src = st_r * 128 + st_c * 16;

  half8 aq[2];
#pragma unroll
  for (int s = 0; s < 2; ++s)
    aq[s] = *(const half8*)&qb[(size_t)(n0 + 16 * w + l16) * 64 + 32 * s + 8 * quad];

  f32x4 o[8][4] = {};
  float m_st[4], l_st[4];
#pragma unroll
  for (int i = 0; i < 4; ++i) { m_st[i] = -1e30f; l_st[i] = 0.f; }

  // QK(block) from K_lds buffer + online softmax -> P buffer; alpha + flag only
  // when this wave's strip raised its running max (rare after defer-max).
  auto qk_softmax = [&](const _Float16* Kb, _Float16* Pb, float* Ab,
                        unsigned char* Fb) {
    f32x4 sc[4];
    __builtin_amdgcn_s_setprio(1);
#pragma unroll
    for (int ct = 0; ct < 4; ++ct) {
      int row = 16 * ct + l16;
      int sw = (row & 7) * 16;
      half8 k0 = *(const half8*)((const char*)Kb + row * 128 + ((quad * 16) ^ sw));
      half8 k1 = *(const half8*)((const char*)Kb + row * 128 + (((4 + quad) * 16) ^ sw));
      f32x4 sa = {0.f, 0.f, 0.f, 0.f};
      sa = __builtin_amdgcn_mfma_f32_16x16x32_f16(aq[0], k0, sa, 0, 0, 0);
      sa = __builtin_amdgcn_mfma_f32_16x16x32_f16(aq[1], k1, sa, 0, 0, 0);
      sc[ct] = sa;
    }
    __builtin_amdgcn_s_setprio(0);
    float a_loc[4];
    bool raised = false;
#pragma unroll
    for (int i = 0; i < 4; ++i) {
      float lmax = fmaxf(fmaxf(sc[0][i], sc[1][i]), fmaxf(sc[2][i], sc[3][i]));
      a_loc[i] = 1.f;
      if (__any(lmax > m_st[i] + 8.f)) {     // rare: full reduce + possible raise
        float mxi = lmax;
#pragma unroll
        for (int off = 1; off < 16; off <<= 1) mxi = fmaxf(mxi, __shfl_xor(mxi, off));
        if (mxi > m_st[i] + 8.f) {           // group-uniform decision
          a_loc[i] = exp2f(m_st[i] - mxi);
          m_st[i] = mxi;
          raised = true;
        }
      }
      float rsum = 0.f;
#pragma unroll
      for (int ct = 0; ct < 4; ++ct) {
        float pv = exp2f(sc[ct][i] - m_st[i]);
        Pb[(16 * w + 4 * quad + i) * 72 + 16 * ct + l16] = (_Float16)pv;
        rsum += pv;
      }
      l_st[i] = l_st[i] * a_loc[i] + rsum;
    }
    bool wr = __any(raised);
    if (wr && l16 == 0) {
#pragma unroll
      for (int i = 0; i < 4; ++i) Ab[16 * w + 4 * quad + i] = a_loc[i];
    }
    if (lane == 0) Fb[w] = wr ? 1 : 0;
  };

  auto rescale = [&](const float* Ab, const unsigned char* Fb) {
    unsigned long long f = *(const unsigned long long*)Fb;  // wave-uniform
    if (f) {
#pragma unroll
      for (int rt = 0; rt < 8; ++rt) {
        if ((f >> (8 * rt)) & 0xffULL) {
          f32x4 ar = *(const f32x4*)&Ab[16 * rt + 4 * quad];
#pragma unroll
          for (int c2 = 0; c2 < 4; ++c2)
#pragma unroll
            for (int i = 0; i < 4; ++i) o[rt][c2][i] *= ar[i];
        }
      }
    }
  };

  // PV from P buffer + vreg; reload vreg for m-offset mn as each pair is consumed
  half8 vreg[8];
  auto pv_step = [&](const _Float16* Pb, int mn) {
    __builtin_amdgcn_s_setprio(1);
#pragma unroll
    for (int rt = 0; rt < 8; ++rt) {
      half8 pa0 = *(const half8*)&Pb[(16 * rt + l16) * 72 + 8 * quad];
      half8 pa1 = *(const half8*)&Pb[(16 * rt + l16) * 72 + 32 + 8 * quad];
#pragma unroll
      for (int c2 = 0; c2 < 4; ++c2) {
        o[rt][c2] = __builtin_amdgcn_mfma_f32_16x16x32_f16(pa0, vreg[2 * c2], o[rt][c2], 0, 0, 0);
        o[rt][c2] = __builtin_amdgcn_mfma_f32_16x16x32_f16(pa1, vreg[2 * c2 + 1], o[rt][c2], 0, 0, 0);
      }
    }
    __builtin_amdgcn_s_setprio(0);
#pragma unroll
    for (int c2 = 0; c2 < 4; ++c2) {
      vreg[2 * c2]     = *(const half8*)&vp[c2 * 65536 + mn];
      vreg[2 * c2 + 1] = *(const half8*)&vp[c2 * 65536 + mn + 32];
    }
  };

  // ---- prologue: V(0) prefetch; K(0)->buf0, K(1)->buf1; QK(0)+softmax(0) ----
#pragma unroll
  for (int c2 = 0; c2 < 4; ++c2)
#pragma unroll
    for (int s = 0; s < 2; ++s)
      vreg[2 * c2 + s] = *(const half8*)&vp[c2 * 65536 + 32 * s];
  async_copy16(kbb + st_src, (char*)K_lds[0] + st_dst);
  async_copy16(kbb + 64 * 128 + st_src, (char*)K_lds[1] + st_dst);
  __syncthreads();
  qk_softmax(K_lds[0], P_lds[0], alpha_lds[0], aflag[0]);

#pragma unroll 1
  for (int it = 0; it < 63; ++it) {
    int cur = it & 1, nxt = cur ^ 1;
    __syncthreads();  // P(it)/alpha(it)/flags visible; K(it+1) staged; PV(it-1) done
    int ms = (it + 2 < 64 ? it + 2 : 63) * 64;
    async_copy16(kbb + (size_t)ms * 128 + st_src, (char*)K_lds[cur] + st_dst);
    rescale(alpha_lds[cur], aflag[cur]);
    if (pv_first) {
      pv_step(P_lds[cur], (it + 1) * 64);
      qk_softmax(K_lds[nxt], P_lds[nxt], alpha_lds[nxt], aflag[nxt]);
    } else {
      qk_softmax(K_lds[nxt], P_lds[nxt], alpha_lds[nxt], aflag[nxt]);
      pv_step(P_lds[cur], (it + 1) * 64);
    }
  }
  // ---- tail: iteration 63 ----
  __syncthreads();
  rescale(alpha_lds[1], aflag[1]);
  pv_step(P_lds[1], 63 * 64);

  // ---- finalize: reduce per-lane l partials, normalize, write ----
#pragma unroll
  for (int i = 0; i < 4; ++i) {
    float s = l_st[i];
#pragma unroll
    for (int off = 1; off < 16; off <<= 1) s += __shfl_xor(s, off);
    if (l16 == 0) l_lds[16 * w + 4 * quad + i] = s;
  }
  __syncthreads();
  float* ob = out + (size_t)b * 512 * 4096;
#pragma unroll
  for (int rt = 0; rt < 8; ++rt) {
    f32x4 lv = *(const f32x4*)&l_lds[16 * rt + 4 * quad];
    f32x4 inv;
#pragma unroll
    for (int i = 0; i < 4; ++i) inv[i] = 1.0f / lv[i];
#pragma unroll
    for (int c2 = 0; c2 < 4; ++c2) {
      int vv = 64 * w + 16 * c2 + l16;
      f32x4 res = o[rt][c2] * inv;
      *(f32x4*)(ob + (size_t)vv * 4096 + n0 + 16 * rt + 4 * quad) = res;
    }
  }
}

// ---------------- launch ----------------
extern "C" void kernel_launch(void* const* d_in, const int* in_sizes, int n_in,
                              void* d_out, int out_size, void* d_ws, size_t ws_size,
                              hipStream_t stream) {
  const float* x     = (const float*)d_in[0];
  const float* Wq    = (const float*)d_in[1];
  const float* bq    = (const float*)d_in[2];
  const float* Wk    = (const float*)d_in[3];
  const float* bk    = (const float*)d_in[4];
  const float* Wv    = (const float*)d_in[5];
  const float* gamma = (const float*)d_in[6];
  const float* beta  = (const float*)d_in[7];
  const float* mean  = (const float*)d_in[8];
  const float* var   = (const float*)d_in[9];
  float* out = (float*)d_out;

  char* ws = (char*)d_ws;
  _Float16* xT     = (_Float16*)(ws);                 // 33,554,432 B
  _Float16* W_all  = (_Float16*)(ws + 33554432);      //    655,360 B
  _Float16* q_buf  = (_Float16*)(ws + 34209792);      //  4,194,304 B
  _Float16* kT_buf = (_Float16*)(ws + 38404096);      //  4,194,304 B
  _Float16* v_buf  = (_Float16*)(ws + 42598400);      // 33,554,432 B -> total 76,152,832 B

  k_transpose<<<dim3(64, 8, 8), 256, 0, stream>>>(x, xT);
  k_wall<<<dim3(1280), 256, 0, stream>>>(Wq, Wk, Wv, W_all);
  k_proj<<<dim3(32, 5, 8), 256, 0, stream>>>(W_all, xT, bq, bk, gamma, beta, mean, var,
                                             q_buf, kT_buf, v_buf);
  k_flash<<<dim3(256), 512, 0, stream>>>(q_buf, kT_buf, v_buf, out);
}